// Round 7
// baseline (187.703 us; speedup 1.0000x reference)
//
#include <hip/hip_runtime.h>

// AlgebraicAttention on MI355X (gfx950), round 17.
// R16 post-mortem: attn Ws-deletion bench-neutral (kept: -17KB LDS); chip clock
// variance ~20% run-to-run on identical code. This round: deepen gemm_qkv's
// load pipeline 4 -> 8. The old single end-of-tile vmcnt(4) drained to 4
// outstanding every tile (covers both k0-staged-2-tiles-ago and k1-staged-this-
// tile). New 2-gate ledger (batches X_T = (T+1).k1 staged ph1/2, Y_T = (T+2).k0
// staged ph3/4; FIFO ... X_{T-1}, Y_{T-1}, X_T, Y_T):
//   ph2-end: vmcnt(8) drains X_{T-1} (buf.k1 for ph3); T==NT-1 -> vmcnt(0).
//   ph4-end: vmcnt(8) drains Y_{T-1} (next buf.k0); T==NT-2 -> vmcnt(4).
//   prologue gate vmcnt(4) -> vmcnt(8).
// Every vmcnt sits right before an existing s_barrier -> cross-wave LDS
// visibility identical to the proven r9/r11 pattern. cast/attn/gemm_out
// byte-identical to r16.
// ws: [0,8M) xb | [8,10M) wqb | [10,12M) wkb | [12,14M) wvb | [14,16M) wob |
//     [16,24M) Qb (att in-place). d_out: [0,8M) Kb | [8,16M) Vtg (V^T).

typedef __attribute__((ext_vector_type(8))) __bf16 bf16x8;
typedef __attribute__((ext_vector_type(4))) __bf16 bf16x4;
typedef __attribute__((ext_vector_type(4))) float f32x4;
typedef __attribute__((ext_vector_type(4))) short s16x4;
typedef unsigned short u16;

__device__ __forceinline__ u16 f2bf(float f) {
  unsigned u = __float_as_uint(f);
  u += 0x7FFFu + ((u >> 16) & 1u);   // round-to-nearest-even
  return (u16)(u >> 16);
}
__device__ __forceinline__ float bf2f(u16 b) {
  return __uint_as_float(((unsigned)b) << 16);
}
__device__ __forceinline__ void gl_lds16(const void* g, void* l) {
  __builtin_amdgcn_global_load_lds((__attribute__((address_space(1))) void*)g,
                                   (__attribute__((address_space(3))) void*)l,
                                   16, 0, 0);
}
// K=16 bf16 MFMA. Builtin path: compiler handles all MFMA hazard wait-states.
__device__ __forceinline__ f32x4 mfma16_bf16(uint2 a, uint2 b, f32x4 c) {
#if __has_builtin(__builtin_amdgcn_mfma_f32_16x16x16bf16_1k)
  union U { uint2 u; s16x4 s; } ua, ub;
  ua.u = a; ub.u = b;
  return __builtin_amdgcn_mfma_f32_16x16x16bf16_1k(ua.s, ub.s, c, 0, 0, 0);
#else
  asm volatile("s_nop 1\n\t"
               "v_mfma_f32_16x16x16_bf16 %0, %1, %2, %0\n\t"
               "s_nop 7"
               : "+v"(c) : "v"(a), "v"(b));
  return c;
#endif
}

// ---------------------------------------------------------------- cast kernel
__global__ __launch_bounds__(256) void cast_all_kernel(
    const float* __restrict__ x,  const float* __restrict__ wq,
    const float* __restrict__ wk, const float* __restrict__ wv,
    const float* __restrict__ wo,
    u16* __restrict__ xb, u16* __restrict__ wqb, u16* __restrict__ wkb,
    u16* __restrict__ wvb, u16* __restrict__ wob) {
  long i4 = (long)blockIdx.x * 256 + threadIdx.x;
  const float* src; u16* dst; long rel;
  if (i4 < 1048576) { src = x; dst = xb; rel = i4; }
  else {
    long j = i4 - 1048576;
    int w = (int)(j >> 18);
    rel = j & 262143;
    src = (w == 0) ? wq : (w == 1) ? wk : (w == 2) ? wv : wo;
    dst = (w == 0) ? wqb : (w == 1) ? wkb : (w == 2) ? wvb : wob;
  }
  float4 v = ((const float4*)src)[rel];
  ushort4 o;
  o.x = f2bf(v.x); o.y = f2bf(v.y); o.z = f2bf(v.z); o.w = f2bf(v.w);
  ((ushort4*)dst)[rel] = o;
}

// ---------------------------------------------------------------- GEMM body (r9, proven)
// C = A @ B^T (+bias). 128x128 tile, BK=64, double-buffered swizzled LDS,
// raw s_barrier + vmcnt(8) pipeline. Kept for gemm_out (256 full-fill blocks).
template <bool STORE_BF16>
__device__ __forceinline__ void gemm_body(
    const u16* __restrict__ A, const u16* __restrict__ B,
    const float* __restrict__ bias, bool rowbias,
    void* __restrict__ Cout, int ldc, int m0, int n0) {
  constexpr int K = 1024;
  constexpr int NT = K / 64;
  __shared__ __align__(16) u16 As[2][128 * 64];
  __shared__ __align__(16) u16 Bs[2][128 * 64];

  const int t = threadIdx.x;
  const int lane = t & 63;
  const int wv = t >> 6;
  const int quad = lane >> 4;
  const int l15 = lane & 15;
  const int wr = wv >> 1, wc = wv & 1;
  const int sw0 = (quad ^ (l15 & 7)) * 8;
  const int sw1 = ((4 + quad) ^ (l15 & 7)) * 8;

  const f32x4 vzero = {0.f, 0.f, 0.f, 0.f};
  f32x4 acc[4][4];
#pragma unroll
  for (int i = 0; i < 4; ++i)
#pragma unroll
    for (int j = 0; j < 4; ++j) acc[i][j] = vzero;

  auto stage = [&](int kt, int bufi) {
#pragma unroll
    for (int p = 0; p < 4; ++p) {
      int idx = t + p * 256;
      int row = idx >> 3, seg = idx & 7;
      int sseg = seg ^ (row & 7);
      gl_lds16(&A[(long)(m0 + row) * K + kt * 64 + sseg * 8], &As[bufi][idx * 8]);
      gl_lds16(&B[(long)(n0 + row) * K + kt * 64 + sseg * 8], &Bs[bufi][idx * 8]);
    }
  };

  stage(0, 0);
  for (int kt = 0; kt < NT; ++kt) {
    const int bufi = kt & 1;
    if (kt + 1 < NT) {
      stage(kt + 1, bufi ^ 1);
      asm volatile("s_waitcnt vmcnt(8)" ::: "memory");
    } else {
      asm volatile("s_waitcnt vmcnt(0)" ::: "memory");
    }
    asm volatile("s_barrier" ::: "memory");
#pragma unroll
    for (int ks = 0; ks < 64; ks += 32) {
      const int sw = ks ? sw1 : sw0;
      bf16x8 af[4], bfg[4];
#pragma unroll
      for (int i = 0; i < 4; ++i)
        af[i] = *(const bf16x8*)&As[bufi][(wr * 64 + i * 16 + l15) * 64 + sw];
#pragma unroll
      for (int j = 0; j < 4; ++j)
        bfg[j] = *(const bf16x8*)&Bs[bufi][(wc * 64 + j * 16 + l15) * 64 + sw];
#pragma unroll
      for (int i = 0; i < 4; ++i)
#pragma unroll
        for (int j = 0; j < 4; ++j)
          acc[i][j] = __builtin_amdgcn_mfma_f32_16x16x32_bf16(af[i], bfg[j], acc[i][j], 0, 0, 0);
    }
    asm volatile("s_barrier" ::: "memory");
  }

  float cb[4];
  if (!rowbias) {
#pragma unroll
    for (int j = 0; j < 4; ++j) cb[j] = bias[n0 + wc * 64 + j * 16 + l15];
  }

#pragma unroll
  for (int i = 0; i < 4; ++i) {
#pragma unroll
    for (int r = 0; r < 4; ++r) {
      int row = m0 + wr * 64 + i * 16 + quad * 4 + r;
      long base = (long)row * ldc + n0 + wc * 64;
      float rb_ = rowbias ? bias[row] : 0.f;
#pragma unroll
      for (int j = 0; j < 4; ++j) {
        float v = acc[i][j][r] + (rowbias ? rb_ : cb[j]);
        if (STORE_BF16) ((u16*)Cout)[base + j * 16 + l15] = f2bf(v);
        else            ((float*)Cout)[base + j * 16 + l15] = v;
      }
    }
  }
}

// ---------------------------------------------------------------- 256x256 8-phase body
// r17: 2-gate deep pipeline (8 loads in flight). Batches per tile T:
// X_T = (T+1).k1 [ph1/2], Y_T = (T+2).k0 [ph3/4]. Gates: ph2-end vmcnt(8)
// (vmcnt(0) at T==NT-1), ph4-end vmcnt(8) (vmcnt(4) at T==NT-2). Each gate
// immediately precedes a barrier -> all waves drained before any wave reads.
template <bool STORE_BF16>
__device__ __forceinline__ void gemm256_body(
    const u16* __restrict__ A, const u16* __restrict__ B,
    const float* __restrict__ bias, bool rowbias,
    void* __restrict__ Cout, int ldc, int m0, int n0) {
  constexpr int K = 1024;
  constexpr int NT = K / 64;      // 16 K-tiles
  __shared__ __align__(16) u16 As[2][2][256 * 32];  // 64 KiB
  __shared__ __align__(16) u16 Bs[2][2][256 * 32];  // 64 KiB

  const int t = threadIdx.x;      // 0..511
  const int lane = t & 63;
  const int wv = t >> 6;          // 0..7
  const int wr = wv >> 2;         // 0..1  (M-half of C)
  const int wc = wv & 3;          // 0..3  (N quarter)
  const int quad = lane >> 4;
  const int l15 = lane & 15;

  const int rA = wr * 128 + l15;
  const int rB = wc * 64 + l15;
  const int baseA = rA * 32 + ((quad ^ ((rA >> 1) & 3)) * 8);
  const int baseB = rB * 32 + ((quad ^ ((rB >> 1) & 3)) * 8);

  const int srow = t >> 2;
  const int sg = (t & 3) ^ ((t >> 3) & 3);
  const long sA = (long)(m0 + srow) * K + sg * 8;
  const long sB = (long)(n0 + srow) * K + sg * 8;

  auto stA = [&](int T_, int kh, int bf_) {
    const u16* s = A + sA + T_ * 64 + kh * 32;
    u16* d = &As[bf_][kh][t * 8];
    gl_lds16(s, d);
    gl_lds16(s + (long)128 * K, d + 4096);
  };
  auto stB = [&](int T_, int kh, int bf_) {
    const u16* s = B + sB + T_ * 64 + kh * 32;
    u16* d = &Bs[bf_][kh][t * 8];
    gl_lds16(s, d);
    gl_lds16(s + (long)128 * K, d + 4096);
  };

  const f32x4 vzero = {0.f, 0.f, 0.f, 0.f};
  f32x4 acc[8][4];
#pragma unroll
  for (int i = 0; i < 8; ++i)
#pragma unroll
    for (int j = 0; j < 4; ++j) acc[i][j] = vzero;

  // prologue: t0.k0 + X_{-1}=t0.k1 + Y_{-1}=t1.k0 in flight; gate drains t0.k0.
  stA(0, 0, 0); stB(0, 0, 0);
  stA(0, 1, 0); stB(0, 1, 0);
  stA(1, 0, 1); stB(1, 0, 1);
  asm volatile("s_waitcnt vmcnt(8)" ::: "memory");
  asm volatile("s_barrier" ::: "memory");

  for (int T = 0; T < NT; ++T) {
    const int c = T & 1;
    const u16* Ac = &As[c][0][0];
    const u16* Bc = &Bs[c][0][0];
    bf16x8 af[4], bfr[4];

    // ---- phase 1: khalf 0, C-half 0; prefetch (T+1).A-k1 -> buf c^1 ----
#pragma unroll
    for (int j = 0; j < 4; ++j) bfr[j] = *(const bf16x8*)&Bc[baseB + j * 512];
#pragma unroll
    for (int i = 0; i < 4; ++i) af[i] = *(const bf16x8*)&Ac[baseA + i * 512];
    if (T + 1 < NT) stA(T + 1, 1, c ^ 1);
    asm volatile("s_barrier" ::: "memory");
    __builtin_amdgcn_s_setprio(1);
#pragma unroll
    for (int i = 0; i < 4; ++i)
#pragma unroll
      for (int j = 0; j < 4; ++j)
        acc[i][j] = __builtin_amdgcn_mfma_f32_16x16x32_bf16(af[i], bfr[j], acc[i][j], 0, 0, 0);
    __builtin_amdgcn_s_setprio(0);
    asm volatile("s_barrier" ::: "memory");

    // ---- phase 2: khalf 0, C-half 1 (reuse B frags); prefetch (T+1).B-k1 ----
#pragma unroll
    for (int i = 0; i < 4; ++i) af[i] = *(const bf16x8*)&Ac[baseA + 2048 + i * 512];
    if (T + 1 < NT) stB(T + 1, 1, c ^ 1);
    asm volatile("s_barrier" ::: "memory");
    __builtin_amdgcn_s_setprio(1);
#pragma unroll
    for (int i = 0; i < 4; ++i)
#pragma unroll
      for (int j = 0; j < 4; ++j)
        acc[4 + i][j] = __builtin_amdgcn_mfma_f32_16x16x32_bf16(af[i], bfr[j], acc[4 + i][j], 0, 0, 0);
    __builtin_amdgcn_s_setprio(0);
    // gate A: drain X_{T-1} (= this buf's k1, read in ph3). Last tile: full drain.
    if (T == NT - 1) asm volatile("s_waitcnt vmcnt(0)" ::: "memory");
    else             asm volatile("s_waitcnt vmcnt(8)" ::: "memory");
    asm volatile("s_barrier" ::: "memory");

    // ---- phase 3: khalf 1, C-half 0; prefetch (T+2).A-k0 -> buf c ----
#pragma unroll
    for (int j = 0; j < 4; ++j) bfr[j] = *(const bf16x8*)&Bc[8192 + baseB + j * 512];
#pragma unroll
    for (int i = 0; i < 4; ++i) af[i] = *(const bf16x8*)&Ac[8192 + baseA + i * 512];
    if (T + 2 < NT) stA(T + 2, 0, c);
    asm volatile("s_barrier" ::: "memory");
    __builtin_amdgcn_s_setprio(1);
#pragma unroll
    for (int i = 0; i < 4; ++i)
#pragma unroll
      for (int j = 0; j < 4; ++j)
        acc[i][j] = __builtin_amdgcn_mfma_f32_16x16x32_bf16(af[i], bfr[j], acc[i][j], 0, 0, 0);
    __builtin_amdgcn_s_setprio(0);
    asm volatile("s_barrier" ::: "memory");

    // ---- phase 4: khalf 1, C-half 1; prefetch (T+2).B-k0 ----
#pragma unroll
    for (int i = 0; i < 4; ++i) af[i] = *(const bf16x8*)&Ac[8192 + baseA + 2048 + i * 512];
    if (T + 2 < NT) stB(T + 2, 0, c);
    asm volatile("s_barrier" ::: "memory");
    __builtin_amdgcn_s_setprio(1);
#pragma unroll
    for (int i = 0; i < 4; ++i)
#pragma unroll
      for (int j = 0; j < 4; ++j)
        acc[4 + i][j] = __builtin_amdgcn_mfma_f32_16x16x32_bf16(af[i], bfr[j], acc[4 + i][j], 0, 0, 0);
    __builtin_amdgcn_s_setprio(0);
    // gate B: drain Y_{T-1} (= next buf's k0, read in T+1 ph1). At T==NT-2,
    // Y_{NT-2} was never issued -> shrink count to still drain Y_{NT-3}.
    if (T == NT - 2)     asm volatile("s_waitcnt vmcnt(4)" ::: "memory");
    else if (T < NT - 2) asm volatile("s_waitcnt vmcnt(8)" ::: "memory");
    asm volatile("s_barrier" ::: "memory");
  }

  float cb[4];
  if (!rowbias) {
#pragma unroll
    for (int j = 0; j < 4; ++j) cb[j] = bias[n0 + wc * 64 + j * 16 + l15];
  }

#pragma unroll
  for (int mf = 0; mf < 8; ++mf) {
#pragma unroll
    for (int r = 0; r < 4; ++r) {
      int row = m0 + wr * 128 + mf * 16 + quad * 4 + r;
      long base = (long)row * ldc + n0 + wc * 64;
      float rb_ = rowbias ? bias[row] : 0.f;
#pragma unroll
      for (int j = 0; j < 4; ++j) {
        float v = acc[mf][j][r] + (rowbias ? rb_ : cb[j]);
        if (STORE_BF16) ((u16*)Cout)[base + j * 16 + l15] = f2bf(v);
        else            ((float*)Cout)[base + j * 16 + l15] = v;
      }
    }
  }
}

// ---------------------------------------------------------------- fused QKV + V^T GEMM
__global__ __launch_bounds__(512, 2) void gemm_qkv(
    const u16* __restrict__ xb, const u16* __restrict__ wqb,
    const u16* __restrict__ wkb, const u16* __restrict__ wvb,
    const float* __restrict__ bq, const float* __restrict__ bk,
    const float* __restrict__ bv,
    u16* __restrict__ Qb, u16* __restrict__ Kb, u16* __restrict__ Vtg) {
  const int bx = blockIdx.x;
  const int L = (bx & 7) * 24 + (bx >> 3);
  const u16 *AT, *BT;
  const float* bias;
  u16* C;
  int m0, n0, ldc;
  bool rowbias;
  if (L < 128) {
    int sel = L >> 6;      // 0 = Q, 1 = K
    int g = L & 63;
    m0 = (g >> 2) * 256; n0 = (g & 3) * 256;
    AT = xb; BT = sel ? wkb : wqb; bias = sel ? bk : bq;
    C = sel ? Kb : Qb; ldc = 1024; rowbias = false;
  } else {
    int g = L - 128;
    m0 = (g & 3) * 256; n0 = (g >> 2) * 256;
    AT = wvb; BT = xb; bias = bv;
    C = Vtg; ldc = 4096; rowbias = true;
  }
  gemm256_body<true>(AT, BT, bias, rowbias, C, ldc, m0, n0);
}

// ---------------------------------------------------------------- output GEMM
__global__ __launch_bounds__(256) void gemm_out(
    const u16* __restrict__ A, const u16* __restrict__ B,
    const float* __restrict__ bias, float* __restrict__ C) {
  gemm_body<false>(A, B, bias, false, C, 1024, blockIdx.x * 128, blockIdx.y * 128);
}

// ---------------------------------------------------------------- attention
// r16 (passed): 512 threads = 8 waves; strip = bx<256 ? 7-(bx>>6) : (bx-256)>>6.
// Wave wv owns q rows strip*128+wv*16..+15. Chunks 0..2*strip+1; fast path for
// c <= 2*strip-2. K/V via double-buffered global_load_lds (pre-swizzled source).
// PV: K=16 MFMA per key-group g directly from QK^T C-layout regs (Ws LDS
// round-trip deleted). Last chunk: waves 0-3 fully masked -> skip.
__global__ __launch_bounds__(512) void attn_strip(
    const u16* __restrict__ Qb,     // [4096][1024]
    const u16* __restrict__ Kb,     // [4096][1024]
    const u16* __restrict__ Vtg,    // [1024][4096] V^T
    const float* __restrict__ rel_bias,  // [63][16]
    u16* __restrict__ att) {        // == Qb
  __shared__ __align__(16) u16 Kt[2][64 * 64];
  __shared__ __align__(16) u16 Vt[2][64 * 64];
  __shared__ float biasl[64];

  const int bx = blockIdx.x;
  const int strip = (bx < 256) ? (7 - (bx >> 6)) : ((bx - 256) >> 6);
  const int bh = bx & 63;
  const int b = bh >> 4, h = bh & 15;
  const int q0 = strip * 128;
  const int cend = 2 * strip + 1;

  const int t = threadIdx.x;
  const int lane = t & 63;
  const int wv = t >> 6;          // 0..7
  const int quad = lane >> 4;
  const int l15 = lane & 15;

  if (t < 63) biasl[t] = rel_bias[t * 16 + h];
  const float b0c = rel_bias[h];  // clipped bias for dd <= -31

  const int srow = t >> 3;
  const int sseg = (t & 7) ^ (srow & 7);
  const u16* Ksrc = &Kb[(long)(b * 1024 + srow) * 1024 + h * 64 + sseg * 8];
  const u16* Vsrc = &Vtg[(long)(h * 64 + srow) * 4096 + b * 1024 + sseg * 8];

  auto stage = [&](int c, int bufi) {
    const int k0 = c * 64;
    gl_lds16(Ksrc + (long)k0 * 1024, &Kt[bufi][t * 8]);
    gl_lds16(Vsrc + k0,              &Vt[bufi][t * 8]);
  };

  const long qrow = (long)(b * 1024 + q0 + wv * 16 + l15) * 1024 + h * 64;
  bf16x8 qf0 = *(const bf16x8*)&Qb[qrow + quad * 8];
  bf16x8 qf1 = *(const bf16x8*)&Qb[qrow + 32 + quad * 8];

  const f32x4 vzero = {0.f, 0.f, 0.f, 0.f};
  f32x4 acc_o[4];
#pragma unroll
  for (int j = 0; j < 4; ++j) acc_o[j] = vzero;
  float denom = 0.f;
  const float scale = 0.125f;  // 64^-0.5
  const int ql = q0 + wv * 16 + l15;
  const int sw0 = (quad ^ (l15 & 7)) * 8;
  const int sw1 = ((4 + quad) ^ (l15 & 7)) * 8;
  const int co = (quad & 1) * 4;      // V b64 half-granule offset
  const int qh = quad >> 1;

  stage(0, 0);   // drained by the first __syncthreads below

  for (int c = 0; c <= cend; ++c) {
    const int buf = c & 1;
    const int k0 = c * 64;
    __syncthreads();
    if (c + 1 <= cend) stage(c + 1, buf ^ 1);
    if ((c == cend) && (wv < 4)) continue;   // fully masked: all w == 0

    const bool fast = (c <= 2 * strip - 2);
#pragma unroll
    for (int g = 0; g < 4; ++g) {
      const u16* kr = &Kt[buf][(g * 16 + l15) * 64];
      bf16x8 kf0 = *(const bf16x8*)&kr[sw0];
      bf16x8 kf1 = *(const bf16x8*)&kr[sw1];
      f32x4 sT = vzero;
      sT = __builtin_amdgcn_mfma_f32_16x16x32_bf16(kf0, qf0, sT, 0, 0, 0);
      sT = __builtin_amdgcn_mfma_f32_16x16x32_bf16(kf1, qf1, sT, 0, 0, 0);
      const int kgb = k0 + g * 16 + quad * 4;
      union { ushort4 us; uint2 u2; } wa;
      if (fast) {
#pragma unroll
        for (int r = 0; r < 4; ++r) {
          float w = fmaxf(sT[r] * scale + b0c, 0.f) + 1e-6f;
          u16 wb = f2bf(w);
          denom += bf2f(wb);
          ((u16*)&wa.us)[r] = wb;
        }
      } else {
#pragma unroll
        for (int r = 0; r < 4; ++r) {
          int kg = kgb + r;
          int dd = kg - ql;
          dd = dd < -31 ? -31 : (dd > 31 ? 31 : dd);
          float sv = sT[r] * scale + biasl[dd + 31];
          float w = (kg <= ql) ? (fmaxf(sv, 0.f) + 1e-6f) : 0.f;
          u16 wb = f2bf(w);
          denom += bf2f(wb);
          ((u16*)&wa.us)[r] = wb;
        }
      }
      const int gk = 2 * g + qh;
#pragma unroll
      for (int j = 0; j < 4; ++j) {
        const int vr = j * 16 + l15;
        uint2 vb = *(const uint2*)&Vt[buf][vr * 64 + ((gk ^ (vr & 7)) * 8) + co];
        acc_o[j] = mfma16_bf16(wa.u2, vb, acc_o[j]);
      }
    }
  }

  // denom for q=l15: reduce across the 4 quads
  denom += __shfl_xor(denom, 16);
  denom += __shfl_xor(denom, 32);

  float invm = 1.f / (denom + 1e-6f);
  float inv[4];
#pragma unroll
  for (int r = 0; r < 4; ++r) inv[r] = __shfl(invm, quad * 4 + r);
#pragma unroll
  for (int j = 0; j < 4; ++j)
#pragma unroll
    for (int r = 0; r < 4; ++r) {
      int q = q0 + wv * 16 + quad * 4 + r;
      att[(long)(b * 1024 + q) * 1024 + h * 64 + j * 16 + l15] = f2bf(acc_o[j][r] * inv[r]);
    }
}

// ---------------------------------------------------------------- launch
extern "C" void kernel_launch(void* const* d_in, const int* in_sizes, int n_in,
                              void* d_out, int out_size, void* d_ws, size_t ws_size,
                              hipStream_t stream) {
  const float* x  = (const float*)d_in[0];
  const float* Wq = (const float*)d_in[2];
  const float* bq = (const float*)d_in[3];
  const float* Wk = (const float*)d_in[4];
  const float* bk = (const float*)d_in[5];
  const float* Wv = (const float*)d_in[6];
  const float* bv = (const float*)d_in[7];
  const float* Wo = (const float*)d_in[8];
  const float* bo = (const float*)d_in[9];
  const float* rb = (const float*)d_in[10];

  char* ws = (char*)d_ws;
  u16* xb  = (u16*)(ws);
  u16* wqb = (u16*)(ws + (8l  << 20));
  u16* wkb = (u16*)(ws + (10l << 20));
  u16* wvb = (u16*)(ws + (12l << 20));
  u16* wob = (u16*)(ws + (14l << 20));
  u16* Qb  = (u16*)(ws + (16l << 20));
  u16* Kb  = (u16*)d_out;
  u16* Vtg = (u16*)((char*)d_out + (8l << 20));

  cast_all_kernel<<<8192, 256, 0, stream>>>(x, Wq, Wk, Wv, Wo, xb, wqb, wkb, wvb, wob);
  gemm_qkv<<<192, 512, 0, stream>>>(xb, wqb, wkb, wvb, bq, bk, bv, Qb, Kb, Vtg);
  attn_strip<<<512, 512, 0, stream>>>(Qb, Kb, Vtg, rb, Qb);
  gemm_out<<<dim3(32, 8), 256, 0, stream>>>(Qb, wob, bo, (float*)d_out);
}

// Round 8
// 182.947 us; speedup vs baseline: 1.0260x; 1.0260x over previous
//
#include <hip/hip_runtime.h>

// AlgebraicAttention on MI355X (gfx950), round 18.
// R17 post-mortem: deeper vmcnt pipeline neutral (gates were never binding) ->
// gemm_qkv confirmed parked at the m248 K=1024 ceiling after 2 independent
// null schedule changes. This round: gemm_out occupancy. It runs 256 blocks x
// 4 waves = 4 waves/CU (lowest in the pipeline; r13 proved TLP is the lever
// for these latency-bound structures). Retile to 128x64 -> 512 blocks, 48KB
// LDS -> 2 blocks/CU = 8 waves/CU. Same r9 2-phase body (stage -> vmcnt(6) ->
// barrier -> MFMA -> barrier), 4 waves = 2Mx2N, acc[4][2], 6 loads/thread.
// B re-reads double but Wo (2MB) is L2-resident. All else identical to r17.
// ws: [0,8M) xb | [8,10M) wqb | [10,12M) wkb | [12,14M) wvb | [14,16M) wob |
//     [16,24M) Qb (att in-place). d_out: [0,8M) Kb | [8,16M) Vtg (V^T).

typedef __attribute__((ext_vector_type(8))) __bf16 bf16x8;
typedef __attribute__((ext_vector_type(4))) __bf16 bf16x4;
typedef __attribute__((ext_vector_type(4))) float f32x4;
typedef __attribute__((ext_vector_type(4))) short s16x4;
typedef unsigned short u16;

__device__ __forceinline__ u16 f2bf(float f) {
  unsigned u = __float_as_uint(f);
  u += 0x7FFFu + ((u >> 16) & 1u);   // round-to-nearest-even
  return (u16)(u >> 16);
}
__device__ __forceinline__ float bf2f(u16 b) {
  return __uint_as_float(((unsigned)b) << 16);
}
__device__ __forceinline__ void gl_lds16(const void* g, void* l) {
  __builtin_amdgcn_global_load_lds((__attribute__((address_space(1))) void*)g,
                                   (__attribute__((address_space(3))) void*)l,
                                   16, 0, 0);
}
// K=16 bf16 MFMA. Builtin path: compiler handles all MFMA hazard wait-states.
__device__ __forceinline__ f32x4 mfma16_bf16(uint2 a, uint2 b, f32x4 c) {
#if __has_builtin(__builtin_amdgcn_mfma_f32_16x16x16bf16_1k)
  union U { uint2 u; s16x4 s; } ua, ub;
  ua.u = a; ub.u = b;
  return __builtin_amdgcn_mfma_f32_16x16x16bf16_1k(ua.s, ub.s, c, 0, 0, 0);
#else
  asm volatile("s_nop 1\n\t"
               "v_mfma_f32_16x16x16_bf16 %0, %1, %2, %0\n\t"
               "s_nop 7"
               : "+v"(c) : "v"(a), "v"(b));
  return c;
#endif
}

// ---------------------------------------------------------------- cast kernel
__global__ __launch_bounds__(256) void cast_all_kernel(
    const float* __restrict__ x,  const float* __restrict__ wq,
    const float* __restrict__ wk, const float* __restrict__ wv,
    const float* __restrict__ wo,
    u16* __restrict__ xb, u16* __restrict__ wqb, u16* __restrict__ wkb,
    u16* __restrict__ wvb, u16* __restrict__ wob) {
  long i4 = (long)blockIdx.x * 256 + threadIdx.x;
  const float* src; u16* dst; long rel;
  if (i4 < 1048576) { src = x; dst = xb; rel = i4; }
  else {
    long j = i4 - 1048576;
    int w = (int)(j >> 18);
    rel = j & 262143;
    src = (w == 0) ? wq : (w == 1) ? wk : (w == 2) ? wv : wo;
    dst = (w == 0) ? wqb : (w == 1) ? wkb : (w == 2) ? wvb : wob;
  }
  float4 v = ((const float4*)src)[rel];
  ushort4 o;
  o.x = f2bf(v.x); o.y = f2bf(v.y); o.z = f2bf(v.z); o.w = f2bf(v.w);
  ((ushort4*)dst)[rel] = o;
}

// ---------------------------------------------------------------- 128x64 GEMM body (r18)
// C = A @ B^T + colbias, fp32 out. 128x64 tile, BK=64, 256 threads = 4 waves
// (2M x 2N), double-buffered swizzled LDS (48KB -> 2 blocks/CU), r9-pattern
// s_barrier + vmcnt(6) pipeline. 6 granule-loads/thread/tile (A:4, B:2).
__device__ __forceinline__ void gemm_n64_body(
    const u16* __restrict__ A, const u16* __restrict__ B,
    const float* __restrict__ bias, float* __restrict__ Cout,
    int ldc, int m0, int n0) {
  constexpr int K = 1024;
  constexpr int NT = K / 64;
  __shared__ __align__(16) u16 As[2][128 * 64];
  __shared__ __align__(16) u16 Bs[2][64 * 64];

  const int t = threadIdx.x;
  const int lane = t & 63;
  const int wv = t >> 6;          // 0..3
  const int quad = lane >> 4;
  const int l15 = lane & 15;
  const int wr = wv >> 1, wc = wv & 1;
  const int sw0 = (quad ^ (l15 & 7)) * 8;
  const int sw1 = ((4 + quad) ^ (l15 & 7)) * 8;

  const f32x4 vzero = {0.f, 0.f, 0.f, 0.f};
  f32x4 acc[4][2];
#pragma unroll
  for (int i = 0; i < 4; ++i)
#pragma unroll
    for (int j = 0; j < 2; ++j) acc[i][j] = vzero;

  auto stage = [&](int kt, int bufi) {
#pragma unroll
    for (int p = 0; p < 4; ++p) {
      int idx = t + p * 256;
      int row = idx >> 3, seg = idx & 7;
      int sseg = seg ^ (row & 7);
      gl_lds16(&A[(long)(m0 + row) * K + kt * 64 + sseg * 8], &As[bufi][idx * 8]);
    }
#pragma unroll
    for (int p = 0; p < 2; ++p) {
      int idx = t + p * 256;
      int row = idx >> 3, seg = idx & 7;
      int sseg = seg ^ (row & 7);
      gl_lds16(&B[(long)(n0 + row) * K + kt * 64 + sseg * 8], &Bs[bufi][idx * 8]);
    }
  };

  stage(0, 0);
  for (int kt = 0; kt < NT; ++kt) {
    const int bufi = kt & 1;
    if (kt + 1 < NT) {
      stage(kt + 1, bufi ^ 1);
      asm volatile("s_waitcnt vmcnt(6)" ::: "memory");
    } else {
      asm volatile("s_waitcnt vmcnt(0)" ::: "memory");
    }
    asm volatile("s_barrier" ::: "memory");
#pragma unroll
    for (int ks = 0; ks < 64; ks += 32) {
      const int sw = ks ? sw1 : sw0;
      bf16x8 af[4], bfg[2];
#pragma unroll
      for (int i = 0; i < 4; ++i)
        af[i] = *(const bf16x8*)&As[bufi][(wr * 64 + i * 16 + l15) * 64 + sw];
#pragma unroll
      for (int j = 0; j < 2; ++j)
        bfg[j] = *(const bf16x8*)&Bs[bufi][(wc * 32 + j * 16 + l15) * 64 + sw];
#pragma unroll
      for (int i = 0; i < 4; ++i)
#pragma unroll
        for (int j = 0; j < 2; ++j)
          acc[i][j] = __builtin_amdgcn_mfma_f32_16x16x32_bf16(af[i], bfg[j], acc[i][j], 0, 0, 0);
    }
    asm volatile("s_barrier" ::: "memory");
  }

  float cb[2];
#pragma unroll
  for (int j = 0; j < 2; ++j) cb[j] = bias[n0 + wc * 32 + j * 16 + l15];

#pragma unroll
  for (int i = 0; i < 4; ++i) {
#pragma unroll
    for (int r = 0; r < 4; ++r) {
      int row = m0 + wr * 64 + i * 16 + quad * 4 + r;
      long base = (long)row * ldc + n0 + wc * 32;
#pragma unroll
      for (int j = 0; j < 2; ++j)
        Cout[base + j * 16 + l15] = acc[i][j][r] + cb[j];
    }
  }
}

// ---------------------------------------------------------------- 256x256 8-phase body
// r17 schedule (2-gate, 8 in flight). Parked at the m248 K=1024 ceiling.
template <bool STORE_BF16>
__device__ __forceinline__ void gemm256_body(
    const u16* __restrict__ A, const u16* __restrict__ B,
    const float* __restrict__ bias, bool rowbias,
    void* __restrict__ Cout, int ldc, int m0, int n0) {
  constexpr int K = 1024;
  constexpr int NT = K / 64;      // 16 K-tiles
  __shared__ __align__(16) u16 As[2][2][256 * 32];  // 64 KiB
  __shared__ __align__(16) u16 Bs[2][2][256 * 32];  // 64 KiB

  const int t = threadIdx.x;      // 0..511
  const int lane = t & 63;
  const int wv = t >> 6;          // 0..7
  const int wr = wv >> 2;         // 0..1  (M-half of C)
  const int wc = wv & 3;          // 0..3  (N quarter)
  const int quad = lane >> 4;
  const int l15 = lane & 15;

  const int rA = wr * 128 + l15;
  const int rB = wc * 64 + l15;
  const int baseA = rA * 32 + ((quad ^ ((rA >> 1) & 3)) * 8);
  const int baseB = rB * 32 + ((quad ^ ((rB >> 1) & 3)) * 8);

  const int srow = t >> 2;
  const int sg = (t & 3) ^ ((t >> 3) & 3);
  const long sA = (long)(m0 + srow) * K + sg * 8;
  const long sB = (long)(n0 + srow) * K + sg * 8;

  auto stA = [&](int T_, int kh, int bf_) {
    const u16* s = A + sA + T_ * 64 + kh * 32;
    u16* d = &As[bf_][kh][t * 8];
    gl_lds16(s, d);
    gl_lds16(s + (long)128 * K, d + 4096);
  };
  auto stB = [&](int T_, int kh, int bf_) {
    const u16* s = B + sB + T_ * 64 + kh * 32;
    u16* d = &Bs[bf_][kh][t * 8];
    gl_lds16(s, d);
    gl_lds16(s + (long)128 * K, d + 4096);
  };

  const f32x4 vzero = {0.f, 0.f, 0.f, 0.f};
  f32x4 acc[8][4];
#pragma unroll
  for (int i = 0; i < 8; ++i)
#pragma unroll
    for (int j = 0; j < 4; ++j) acc[i][j] = vzero;

  stA(0, 0, 0); stB(0, 0, 0);
  stA(0, 1, 0); stB(0, 1, 0);
  stA(1, 0, 1); stB(1, 0, 1);
  asm volatile("s_waitcnt vmcnt(8)" ::: "memory");
  asm volatile("s_barrier" ::: "memory");

  for (int T = 0; T < NT; ++T) {
    const int c = T & 1;
    const u16* Ac = &As[c][0][0];
    const u16* Bc = &Bs[c][0][0];
    bf16x8 af[4], bfr[4];

    // ---- phase 1: khalf 0, C-half 0; prefetch (T+1).A-k1 -> buf c^1 ----
#pragma unroll
    for (int j = 0; j < 4; ++j) bfr[j] = *(const bf16x8*)&Bc[baseB + j * 512];
#pragma unroll
    for (int i = 0; i < 4; ++i) af[i] = *(const bf16x8*)&Ac[baseA + i * 512];
    if (T + 1 < NT) stA(T + 1, 1, c ^ 1);
    asm volatile("s_barrier" ::: "memory");
    __builtin_amdgcn_s_setprio(1);
#pragma unroll
    for (int i = 0; i < 4; ++i)
#pragma unroll
      for (int j = 0; j < 4; ++j)
        acc[i][j] = __builtin_amdgcn_mfma_f32_16x16x32_bf16(af[i], bfr[j], acc[i][j], 0, 0, 0);
    __builtin_amdgcn_s_setprio(0);
    asm volatile("s_barrier" ::: "memory");

    // ---- phase 2: khalf 0, C-half 1 (reuse B frags); prefetch (T+1).B-k1 ----
#pragma unroll
    for (int i = 0; i < 4; ++i) af[i] = *(const bf16x8*)&Ac[baseA + 2048 + i * 512];
    if (T + 1 < NT) stB(T + 1, 1, c ^ 1);
    asm volatile("s_barrier" ::: "memory");
    __builtin_amdgcn_s_setprio(1);
#pragma unroll
    for (int i = 0; i < 4; ++i)
#pragma unroll
      for (int j = 0; j < 4; ++j)
        acc[4 + i][j] = __builtin_amdgcn_mfma_f32_16x16x32_bf16(af[i], bfr[j], acc[4 + i][j], 0, 0, 0);
    __builtin_amdgcn_s_setprio(0);
    if (T == NT - 1) asm volatile("s_waitcnt vmcnt(0)" ::: "memory");
    else             asm volatile("s_waitcnt vmcnt(8)" ::: "memory");
    asm volatile("s_barrier" ::: "memory");

    // ---- phase 3: khalf 1, C-half 0; prefetch (T+2).A-k0 -> buf c ----
#pragma unroll
    for (int j = 0; j < 4; ++j) bfr[j] = *(const bf16x8*)&Bc[8192 + baseB + j * 512];
#pragma unroll
    for (int i = 0; i < 4; ++i) af[i] = *(const bf16x8*)&Ac[8192 + baseA + i * 512];
    if (T + 2 < NT) stA(T + 2, 0, c);
    asm volatile("s_barrier" ::: "memory");
    __builtin_amdgcn_s_setprio(1);
#pragma unroll
    for (int i = 0; i < 4; ++i)
#pragma unroll
      for (int j = 0; j < 4; ++j)
        acc[i][j] = __builtin_amdgcn_mfma_f32_16x16x32_bf16(af[i], bfr[j], acc[i][j], 0, 0, 0);
    __builtin_amdgcn_s_setprio(0);
    asm volatile("s_barrier" ::: "memory");

    // ---- phase 4: khalf 1, C-half 1; prefetch (T+2).B-k0 ----
#pragma unroll
    for (int i = 0; i < 4; ++i) af[i] = *(const bf16x8*)&Ac[8192 + baseA + 2048 + i * 512];
    if (T + 2 < NT) stB(T + 2, 0, c);
    asm volatile("s_barrier" ::: "memory");
    __builtin_amdgcn_s_setprio(1);
#pragma unroll
    for (int i = 0; i < 4; ++i)
#pragma unroll
      for (int j = 0; j < 4; ++j)
        acc[4 + i][j] = __builtin_amdgcn_mfma_f32_16x16x32_bf16(af[i], bfr[j], acc[4 + i][j], 0, 0, 0);
    __builtin_amdgcn_s_setprio(0);
    if (T == NT - 2)     asm volatile("s_waitcnt vmcnt(4)" ::: "memory");
    else if (T < NT - 2) asm volatile("s_waitcnt vmcnt(8)" ::: "memory");
    asm volatile("s_barrier" ::: "memory");
  }

  float cb[4];
  if (!rowbias) {
#pragma unroll
    for (int j = 0; j < 4; ++j) cb[j] = bias[n0 + wc * 64 + j * 16 + l15];
  }

#pragma unroll
  for (int mf = 0; mf < 8; ++mf) {
#pragma unroll
    for (int r = 0; r < 4; ++r) {
      int row = m0 + wr * 128 + mf * 16 + quad * 4 + r;
      long base = (long)row * ldc + n0 + wc * 64;
      float rb_ = rowbias ? bias[row] : 0.f;
#pragma unroll
      for (int j = 0; j < 4; ++j) {
        float v = acc[mf][j][r] + (rowbias ? rb_ : cb[j]);
        if (STORE_BF16) ((u16*)Cout)[base + j * 16 + l15] = f2bf(v);
        else            ((float*)Cout)[base + j * 16 + l15] = v;
      }
    }
  }
}

// ---------------------------------------------------------------- fused QKV + V^T GEMM
__global__ __launch_bounds__(512, 2) void gemm_qkv(
    const u16* __restrict__ xb, const u16* __restrict__ wqb,
    const u16* __restrict__ wkb, const u16* __restrict__ wvb,
    const float* __restrict__ bq, const float* __restrict__ bk,
    const float* __restrict__ bv,
    u16* __restrict__ Qb, u16* __restrict__ Kb, u16* __restrict__ Vtg) {
  const int bx = blockIdx.x;
  const int L = (bx & 7) * 24 + (bx >> 3);
  const u16 *AT, *BT;
  const float* bias;
  u16* C;
  int m0, n0, ldc;
  bool rowbias;
  if (L < 128) {
    int sel = L >> 6;      // 0 = Q, 1 = K
    int g = L & 63;
    m0 = (g >> 2) * 256; n0 = (g & 3) * 256;
    AT = xb; BT = sel ? wkb : wqb; bias = sel ? bk : bq;
    C = sel ? Kb : Qb; ldc = 1024; rowbias = false;
  } else {
    int g = L - 128;
    m0 = (g & 3) * 256; n0 = (g >> 2) * 256;
    AT = wvb; BT = xb; bias = bv;
    C = Vtg; ldc = 4096; rowbias = true;
  }
  gemm256_body<true>(AT, BT, bias, rowbias, C, ldc, m0, n0);
}

// ---------------------------------------------------------------- output GEMM
// r18: 128x64 tiles -> 512 blocks, 2 blocks/CU (8 waves/CU, was 4).
__global__ __launch_bounds__(256) void gemm_out(
    const u16* __restrict__ A, const u16* __restrict__ B,
    const float* __restrict__ bias, float* __restrict__ C) {
  gemm_n64_body(A, B, bias, C, 1024, blockIdx.x * 128, blockIdx.y * 64);
}

// ---------------------------------------------------------------- attention
// r16 (passed): 512 threads = 8 waves; strip = bx<256 ? 7-(bx>>6) : (bx-256)>>6.
// Wave wv owns q rows strip*128+wv*16..+15. Chunks 0..2*strip+1; fast path for
// c <= 2*strip-2. K/V via double-buffered global_load_lds (pre-swizzled source).
// PV: K=16 MFMA per key-group g directly from QK^T C-layout regs (Ws LDS
// round-trip deleted). Last chunk: waves 0-3 fully masked -> skip.
__global__ __launch_bounds__(512) void attn_strip(
    const u16* __restrict__ Qb,     // [4096][1024]
    const u16* __restrict__ Kb,     // [4096][1024]
    const u16* __restrict__ Vtg,    // [1024][4096] V^T
    const float* __restrict__ rel_bias,  // [63][16]
    u16* __restrict__ att) {        // == Qb
  __shared__ __align__(16) u16 Kt[2][64 * 64];
  __shared__ __align__(16) u16 Vt[2][64 * 64];
  __shared__ float biasl[64];

  const int bx = blockIdx.x;
  const int strip = (bx < 256) ? (7 - (bx >> 6)) : ((bx - 256) >> 6);
  const int bh = bx & 63;
  const int b = bh >> 4, h = bh & 15;
  const int q0 = strip * 128;
  const int cend = 2 * strip + 1;

  const int t = threadIdx.x;
  const int lane = t & 63;
  const int wv = t >> 6;          // 0..7
  const int quad = lane >> 4;
  const int l15 = lane & 15;

  if (t < 63) biasl[t] = rel_bias[t * 16 + h];
  const float b0c = rel_bias[h];  // clipped bias for dd <= -31

  const int srow = t >> 3;
  const int sseg = (t & 7) ^ (srow & 7);
  const u16* Ksrc = &Kb[(long)(b * 1024 + srow) * 1024 + h * 64 + sseg * 8];
  const u16* Vsrc = &Vtg[(long)(h * 64 + srow) * 4096 + b * 1024 + sseg * 8];

  auto stage = [&](int c, int bufi) {
    const int k0 = c * 64;
    gl_lds16(Ksrc + (long)k0 * 1024, &Kt[bufi][t * 8]);
    gl_lds16(Vsrc + k0,              &Vt[bufi][t * 8]);
  };

  const long qrow = (long)(b * 1024 + q0 + wv * 16 + l15) * 1024 + h * 64;
  bf16x8 qf0 = *(const bf16x8*)&Qb[qrow + quad * 8];
  bf16x8 qf1 = *(const bf16x8*)&Qb[qrow + 32 + quad * 8];

  const f32x4 vzero = {0.f, 0.f, 0.f, 0.f};
  f32x4 acc_o[4];
#pragma unroll
  for (int j = 0; j < 4; ++j) acc_o[j] = vzero;
  float denom = 0.f;
  const float scale = 0.125f;  // 64^-0.5
  const int ql = q0 + wv * 16 + l15;
  const int sw0 = (quad ^ (l15 & 7)) * 8;
  const int sw1 = ((4 + quad) ^ (l15 & 7)) * 8;
  const int co = (quad & 1) * 4;      // V b64 half-granule offset
  const int qh = quad >> 1;

  stage(0, 0);   // drained by the first __syncthreads below

  for (int c = 0; c <= cend; ++c) {
    const int buf = c & 1;
    const int k0 = c * 64;
    __syncthreads();
    if (c + 1 <= cend) stage(c + 1, buf ^ 1);
    if ((c == cend) && (wv < 4)) continue;   // fully masked: all w == 0

    const bool fast = (c <= 2 * strip - 2);
#pragma unroll
    for (int g = 0; g < 4; ++g) {
      const u16* kr = &Kt[buf][(g * 16 + l15) * 64];
      bf16x8 kf0 = *(const bf16x8*)&kr[sw0];
      bf16x8 kf1 = *(const bf16x8*)&kr[sw1];
      f32x4 sT = vzero;
      sT = __builtin_amdgcn_mfma_f32_16x16x32_bf16(kf0, qf0, sT, 0, 0, 0);
      sT = __builtin_amdgcn_mfma_f32_16x16x32_bf16(kf1, qf1, sT, 0, 0, 0);
      const int kgb = k0 + g * 16 + quad * 4;
      union { ushort4 us; uint2 u2; } wa;
      if (fast) {
#pragma unroll
        for (int r = 0; r < 4; ++r) {
          float w = fmaxf(sT[r] * scale + b0c, 0.f) + 1e-6f;
          u16 wb = f2bf(w);
          denom += bf2f(wb);
          ((u16*)&wa.us)[r] = wb;
        }
      } else {
#pragma unroll
        for (int r = 0; r < 4; ++r) {
          int kg = kgb + r;
          int dd = kg - ql;
          dd = dd < -31 ? -31 : (dd > 31 ? 31 : dd);
          float sv = sT[r] * scale + biasl[dd + 31];
          float w = (kg <= ql) ? (fmaxf(sv, 0.f) + 1e-6f) : 0.f;
          u16 wb = f2bf(w);
          denom += bf2f(wb);
          ((u16*)&wa.us)[r] = wb;
        }
      }
      const int gk = 2 * g + qh;
#pragma unroll
      for (int j = 0; j < 4; ++j) {
        const int vr = j * 16 + l15;
        uint2 vb = *(const uint2*)&Vt[buf][vr * 64 + ((gk ^ (vr & 7)) * 8) + co];
        acc_o[j] = mfma16_bf16(wa.u2, vb, acc_o[j]);
      }
    }
  }

  // denom for q=l15: reduce across the 4 quads
  denom += __shfl_xor(denom, 16);
  denom += __shfl_xor(denom, 32);

  float invm = 1.f / (denom + 1e-6f);
  float inv[4];
#pragma unroll
  for (int r = 0; r < 4; ++r) inv[r] = __shfl(invm, quad * 4 + r);
#pragma unroll
  for (int j = 0; j < 4; ++j)
#pragma unroll
    for (int r = 0; r < 4; ++r) {
      int q = q0 + wv * 16 + quad * 4 + r;
      att[(long)(b * 1024 + q) * 1024 + h * 64 + j * 16 + l15] = f2bf(acc_o[j][r] * inv[r]);
    }
}

// ---------------------------------------------------------------- launch
extern "C" void kernel_launch(void* const* d_in, const int* in_sizes, int n_in,
                              void* d_out, int out_size, void* d_ws, size_t ws_size,
                              hipStream_t stream) {
  const float* x  = (const float*)d_in[0];
  const float* Wq = (const float*)d_in[2];
  const float* bq = (const float*)d_in[3];
  const float* Wk = (const float*)d_in[4];
  const float* bk = (const float*)d_in[5];
  const float* Wv = (const float*)d_in[6];
  const float* bv = (const float*)d_in[7];
  const float* Wo = (const float*)d_in[8];
  const float* bo = (const float*)d_in[9];
  const float* rb = (const float*)d_in[10];

  char* ws = (char*)d_ws;
  u16* xb  = (u16*)(ws);
  u16* wqb = (u16*)(ws + (8l  << 20));
  u16* wkb = (u16*)(ws + (10l << 20));
  u16* wvb = (u16*)(ws + (12l << 20));
  u16* wob = (u16*)(ws + (14l << 20));
  u16* Qb  = (u16*)(ws + (16l << 20));
  u16* Kb  = (u16*)d_out;
  u16* Vtg = (u16*)((char*)d_out + (8l << 20));

  cast_all_kernel<<<8192, 256, 0, stream>>>(x, Wq, Wk, Wv, Wo, xb, wqb, wkb, wvb, wob);
  gemm_qkv<<<192, 512, 0, stream>>>(xb, wqb, wkb, wvb, bq, bk, bv, Qb, Kb, Vtg);
  attn_strip<<<512, 512, 0, stream>>>(Qb, Kb, Vtg, rb, Qb);
  gemm_out<<<dim3(32, 16), 256, 0, stream>>>(Qb, wob, bo, (float*)d_out);
}